// Round 5
// baseline (498.230 us; speedup 1.0000x reference)
//
#include <hip/hip_runtime.h>
#include <hip/hip_bf16.h>
#include <hip/hip_fp8.h>

typedef unsigned char  u8;
typedef unsigned short u16;
typedef unsigned int   u32;
typedef unsigned long long u64;
typedef __attribute__((ext_vector_type(8)))  short bf16x8;
typedef __attribute__((ext_vector_type(4)))  float f32x4;
typedef __attribute__((ext_vector_type(16))) float f32x16;
typedef __attribute__((ext_vector_type(4)))  u16   u16x4;
typedef __attribute__((ext_vector_type(8)))  int   i32x8;

__device__ __forceinline__ u16 f2bf(float f) {
  union { float f; u32 u; } v; v.f = f;
  u32 r = v.u + 0x7FFFu + ((v.u >> 16) & 1u);   // RNE
  return (u16)(r >> 16);
}

// pack 2 floats into fp8 e4m3 pair (WORD=false: low 16 bits of old; true: high)
template <bool WORD>
__device__ __forceinline__ u32 pk_fp8(float a, float b, u32 old) {
#if __has_builtin(__builtin_amdgcn_cvt_pk_fp8_f32)
  return (u32)__builtin_amdgcn_cvt_pk_fp8_f32(a, b, (int)old, WORD);
#else
  __hip_fp8_e4m3 x(a), y(b);
  u32 v = (u32)x.__x | ((u32)y.__x << 8);
  return WORD ? ((old & 0xFFFFu) | (v << 16)) : ((old & 0xFFFF0000u) | v);
#endif
}

#define GLL16(gptr, lptr)                                                            \
  __builtin_amdgcn_global_load_lds((const __attribute__((address_space(1))) u32*)(gptr), \
                                   (__attribute__((address_space(3))) u32*)(lptr), 16, 0, 0)

#define BARRIER_LGKM() do { asm volatile("s_waitcnt lgkmcnt(0)" ::: "memory"); \
                            __builtin_amdgcn_s_barrier(); } while (0)

// ---------------------------------------------------------------- f32 -> bf16
__global__ __launch_bounds__(256) void cvt_bf16(const float* __restrict__ in,
                                                u16* __restrict__ out, int n4) {
  int i = blockIdx.x * blockDim.x + threadIdx.x;
  int stride = gridDim.x * blockDim.x;
  for (; i < n4; i += stride) {
    float4 v = ((const float4*)in)[i];
    u16x4 o = { f2bf(v.x), f2bf(v.y), f2bf(v.z), f2bf(v.w) };
    ((u16x4*)out)[i] = o;
  }
}

// ------------------- keys [16384][768] f32 -> Kf2 fp8, layout [d8=96][key=16384][8B]
__global__ __launch_bounds__(256) void buildK(const float* __restrict__ in,
                                              u8* __restrict__ out) {
  __shared__ float tile[64][65];
  int kt = blockIdx.x;            // 64 keys per block
  int t = threadIdx.x;
  int r0 = t >> 6, c = t & 63;
  for (int dc = 0; dc < 12; ++dc) {
    if (dc) __syncthreads();
#pragma unroll
    for (int i = 0; i < 16; ++i) {
      int r = i * 4 + r0;
      tile[r][c] = in[(size_t)(kt * 64 + r) * 768 + dc * 64 + c];
    }
    __syncthreads();
    int d8l = t >> 5, kl = t & 31;
#pragma unroll
    for (int j = 0; j < 2; ++j) {
      int key = j * 32 + kl;
      float v0 = tile[key][d8l * 8 + 0], v1 = tile[key][d8l * 8 + 1];
      float v2 = tile[key][d8l * 8 + 2], v3 = tile[key][d8l * 8 + 3];
      float v4 = tile[key][d8l * 8 + 4], v5 = tile[key][d8l * 8 + 5];
      float v6 = tile[key][d8l * 8 + 6], v7 = tile[key][d8l * 8 + 7];
      u32 lo = pk_fp8<false>(v0, v1, 0u); lo = pk_fp8<true>(v2, v3, lo);
      u32 hi = pk_fp8<false>(v4, v5, 0u); hi = pk_fp8<true>(v6, v7, hi);
      uint2 val = { lo, hi };
      *(uint2*)(out + (size_t)(dc * 8 + d8l) * 131072 + (size_t)(kt * 64 + key) * 8) = val;
    }
  }
}

// ------------------- values [16384][768] f32 -> Vtf fp8, layout [k8=2048][d=768][8B]
__global__ __launch_bounds__(256) void buildV(const float* __restrict__ in,
                                              u8* __restrict__ out) {
  __shared__ float tile[64][65];
  int kt = blockIdx.x;            // 64 keys per block
  int t = threadIdx.x;
  int r0 = t >> 6, c = t & 63;
  for (int dc = 0; dc < 12; ++dc) {
    if (dc) __syncthreads();
#pragma unroll
    for (int i = 0; i < 16; ++i) {
      int r = i * 4 + r0;
      tile[r][c] = in[(size_t)(kt * 64 + r) * 768 + dc * 64 + c];
    }
    __syncthreads();
    int sub = t >> 5, dl = t & 31;
#pragma unroll
    for (int j = 0; j < 2; ++j) {
      int d = j * 32 + dl;
      float v0 = tile[sub * 8 + 0][d], v1 = tile[sub * 8 + 1][d];
      float v2 = tile[sub * 8 + 2][d], v3 = tile[sub * 8 + 3][d];
      float v4 = tile[sub * 8 + 4][d], v5 = tile[sub * 8 + 5][d];
      float v6 = tile[sub * 8 + 6][d], v7 = tile[sub * 8 + 7][d];
      u32 lo = pk_fp8<false>(v0, v1, 0u); lo = pk_fp8<true>(v2, v3, lo);
      u32 hi = pk_fp8<false>(v4, v5, 0u); hi = pk_fp8<true>(v6, v7, hi);
      uint2 val = { lo, hi };
      *(uint2*)(out + (size_t)(kt * 8 + sub) * 6144 + (size_t)(dc * 64 + d) * 8) = val;
    }
  }
}

// ---------------------------------------------------------------- GEMM1 (bf16)
__global__ __launch_bounds__(256) void gemm1(const u16* __restrict__ A,
                                             const u16* __restrict__ B,
                                             const float* __restrict__ bias,
                                             float* __restrict__ C) {
  __shared__ u16 As[2][128 * 32];
  __shared__ u16 Bs[2][128 * 32];
  int t = threadIdx.x;
  int brow = blockIdx.x * 128, bcol = blockIdx.y * 128;
  int w = t >> 6, l = t & 63;
  int l15 = l & 15, l4 = l >> 4;
  int wr = (w >> 1) * 64, wc = (w & 1) * 64;
  f32x4 acc[4][4];
#pragma unroll
  for (int i = 0; i < 4; ++i)
#pragma unroll
    for (int j = 0; j < 4; ++j) acc[i][j] = f32x4{0.f, 0.f, 0.f, 0.f};

  auto stage = [&](int buf, int kt) {
#pragma unroll
    for (int i = 0; i < 2; ++i) {
      int id = t + i * 256;
      int row = id >> 2, c = id & 3;
      int cs = (c ^ (row & 3)) * 8;
      GLL16(A + (size_t)(brow + row) * 1024 + kt * 32 + cs, &As[buf][id * 8]);
      GLL16(B + (size_t)(bcol + row) * 1024 + kt * 32 + cs, &Bs[buf][id * 8]);
    }
  };
  stage(0, 0);
  for (int kt = 0; kt < 32; ++kt) {
    int buf = kt & 1;
    __syncthreads();
    if (kt < 31) stage(buf ^ 1, kt + 1);
    bf16x8 a[4], b[4];
#pragma unroll
    for (int mf = 0; mf < 4; ++mf) {
      int row = wr + mf * 16 + l15;
      a[mf] = *(const bf16x8*)&As[buf][row * 32 + ((l4 ^ (row & 3)) * 8)];
    }
#pragma unroll
    for (int nf = 0; nf < 4; ++nf) {
      int row = wc + nf * 16 + l15;
      b[nf] = *(const bf16x8*)&Bs[buf][row * 32 + ((l4 ^ (row & 3)) * 8)];
    }
#pragma unroll
    for (int mf = 0; mf < 4; ++mf)
#pragma unroll
      for (int nf = 0; nf < 4; ++nf)
        acc[mf][nf] = __builtin_amdgcn_mfma_f32_16x16x32_bf16(a[mf], b[nf], acc[mf][nf], 0, 0, 0);
  }
#pragma unroll
  for (int mf = 0; mf < 4; ++mf)
#pragma unroll
    for (int nf = 0; nf < 4; ++nf) {
      int col = bcol + wc + nf * 16 + l15;
      float bv = bias[col];
#pragma unroll
      for (int j = 0; j < 4; ++j) {
        int row = brow + wr + mf * 16 + l4 * 4 + j;
        C[(size_t)row * 768 + col] = acc[mf][nf][j] + bv;
      }
    }
}

// ---------------------------------------------------------------- row L2-normalize -> fp8
__global__ __launch_bounds__(384) void rownorm8(const float* __restrict__ P,
                                                u8* __restrict__ pn8) {
  int row = blockIdx.x, t = threadIdx.x;
  size_t base = (size_t)row * 768;
  float2 v = *(const float2*)&P[base + 2 * t];
  float ss = v.x * v.x + v.y * v.y;
#pragma unroll
  for (int o = 32; o; o >>= 1) ss += __shfl_xor(ss, o);
  __shared__ float wsum[6];
  if ((t & 63) == 0) wsum[t >> 6] = ss;
  __syncthreads();
  float tot = wsum[0] + wsum[1] + wsum[2] + wsum[3] + wsum[4] + wsum[5];
  float inv = 1.0f / fmaxf(sqrtf(tot), 1e-12f);
  u32 pk = pk_fp8<false>(v.x * inv, v.y * inv, 0u);
  *(u16*)(pn8 + base + 2 * t) = (u16)(pk & 0xFFFFu);
}

// ---------------------------------------------------------------- fused attention, MX-fp8
// 16 waves (1024 thr), BM=64 q, KVBLK=512 (32 keys/wave QK), nsplit=2, d-slice 48/wave PV.
// QK: mfma_scale_f32_32x32x64_f8f6f4 (unit scales), swapped: A=K(global), B=Q(LDS) -> S^T.
// PV: mfma_scale_f32_16x16x128_f8f6f4 (unit scales): A=P(LDS), B=V(global).
// Unit scale: E8M0 127 = 2^0 -> identical numerics to non-scaled fp8.
// A/B k-map symmetry: both operands use identical (lane-half,byte)->d assignment, so the
// instruction's internal k permutation cancels (same argument validated rounds 3-4).
__global__ __launch_bounds__(1024, 4) void attn(const u8* __restrict__ pn8,
                                                const u8* __restrict__ Kf2,
                                                const u8* __restrict__ Vtf,
                                                const float* __restrict__ beta_p,
                                                u16* __restrict__ Opart,
                                                float* __restrict__ lpart) {
  __shared__ long Qlds[96 * 64];   // 48 KB [c8][q]
  __shared__ long Ps[64 * 64];     // 32 KB [kc8][q], linear in key by construction
  __shared__ float lred[16][64];   // 4 KB
  int t = threadIdx.x;
  int w = t >> 6, l = t & 63;
  int ql = l & 31, hi = l >> 5;        // 32x32 lanes
  int l15 = l & 15, l4g = l >> 4;      // 16x16 lanes (0..3)
  int split = blockIdx.x, qb = blockIdx.y;
  int qrow0 = qb * 64;
  float blog2e = beta_p[0] * 1.44269504089f;

  // ---- stage Q [64 q][768 d] fp8 into [c8][q] (once)
#pragma unroll
  for (int i = 0; i < 6; ++i) {
    int id = i * 1024 + t;
    int c8 = id >> 6, q = id & 63;
    Qlds[c8 * 64 + q] = *(const long*)(pn8 + (size_t)(qrow0 + q) * 768 + (size_t)c8 * 8);
  }

  f32x4 oacc[4][3];
#pragma unroll
  for (int qt = 0; qt < 4; ++qt)
#pragma unroll
    for (int nd = 0; nd < 3; ++nd) oacc[qt][nd] = f32x4{0.f, 0.f, 0.f, 0.f};
  float lsum0 = 0.f, lsum1 = 0.f;

  int kbase = split * 8192;
  const long* Kp = (const long*)Kf2 + (size_t)hi * 16384 + (size_t)(kbase + w * 32 + ql);
  const long* Vp = (const long*)Vtf + ((size_t)(kbase >> 3) + l4g) * 768 + (size_t)(w * 48 + l15);

  __syncthreads();

  for (int it = 0; it < 16; ++it) {
    int n0 = it * 512;
    const long* kp = Kp + n0;

    // ---------- QK^T: wave w -> keys [n0+w*32,+32), all 64 q; 12 steps of K=64 d
    f32x16 sacc0 = (f32x16)0.0f;
    f32x16 sacc1 = (f32x16)0.0f;
    long kb[2][4];
#pragma unroll
    for (int i = 0; i < 4; ++i) {
      kb[0][i] = kp[(size_t)(2 * i) * 16384];
      kb[1][i] = kp[(size_t)(8 + 2 * i) * 16384];
    }
#pragma unroll
    for (int ks = 0; ks < 12; ++ks) {
      union { long l[4]; i32x8 v; } av, q0u, q1u;
#pragma unroll
      for (int i = 0; i < 4; ++i) {
        av.l[i] = kb[ks & 1][i];
        q0u.l[i] = Qlds[(8 * ks + 2 * i + hi) * 64 + ql];
        q1u.l[i] = Qlds[(8 * ks + 2 * i + hi) * 64 + ql + 32];
      }
      if (ks < 10) {
#pragma unroll
        for (int i = 0; i < 4; ++i) kb[ks & 1][i] = kp[(size_t)(8 * (ks + 2) + 2 * i) * 16384];
      }
      sacc0 = __builtin_amdgcn_mfma_scale_f32_32x32x64_f8f6f4(av.v, q0u.v, sacc0,
                                                              0, 0, 0, 127, 0, 127);
      sacc1 = __builtin_amdgcn_mfma_scale_f32_32x32x64_f8f6f4(av.v, q1u.v, sacc1,
                                                              0, 0, 0, 127, 0, 127);
    }

    // ---------- exp (no max), lsum, pack fp8 -> Ps [kc8][q]
    // sacc reg r: key-in-wave = (r&3) + 8*(r>>2) + 4*hi ; q = ql (+32 for sacc1)
#pragma unroll
    for (int qf = 0; qf < 2; ++qf) {
      int q = ql + qf * 32;
      float lacc = 0.f;
#pragma unroll
      for (int rg = 0; rg < 4; ++rg) {
        float p0, p1, p2, p3;
        if (qf == 0) {
          p0 = exp2f(blog2e * sacc0[rg * 4 + 0]); p1 = exp2f(blog2e * sacc0[rg * 4 + 1]);
          p2 = exp2f(blog2e * sacc0[rg * 4 + 2]); p3 = exp2f(blog2e * sacc0[rg * 4 + 3]);
        } else {
          p0 = exp2f(blog2e * sacc1[rg * 4 + 0]); p1 = exp2f(blog2e * sacc1[rg * 4 + 1]);
          p2 = exp2f(blog2e * sacc1[rg * 4 + 2]); p3 = exp2f(blog2e * sacc1[rg * 4 + 3]);
        }
        lacc += (p0 + p1) + (p2 + p3);
        u32 pk = pk_fp8<false>(p0, p1, 0u); pk = pk_fp8<true>(p2, p3, pk);
        ((u32*)Ps)[(w * 4 + rg) * 128 + q * 2 + hi] = pk;
      }
      if (qf == 0) lsum0 += lacc; else lsum1 += lacc;
    }
    BARRIER_LGKM();   // P visible to all waves

    // ---------- PV: O[64 q][48 d per wave] += P * V  (16x16x128, 4 ksteps of 128 keys)
#pragma unroll
    for (int ks = 0; ks < 4; ++ks) {
      union { long l[4]; i32x8 v; } vb0, vb1, vb2;
#pragma unroll
      for (int i = 0; i < 4; ++i) {
        size_t k8o = ((size_t)(n0 >> 3) + 16 * ks + 4 * i) * 768;
        vb0.l[i] = Vp[k8o];
        vb1.l[i] = Vp[k8o + 16];
        vb2.l[i] = Vp[k8o + 32];
      }
#pragma unroll
      for (int qt = 0; qt < 4; ++qt) {
        union { long l[4]; i32x8 v; } pa;
#pragma unroll
        for (int i = 0; i < 4; ++i)
          pa.l[i] = Ps[(16 * ks + 4 * i + l4g) * 64 + qt * 16 + l15];
        oacc[qt][0] = __builtin_amdgcn_mfma_scale_f32_16x16x128_f8f6f4(pa.v, vb0.v, oacc[qt][0],
                                                                       0, 0, 0, 127, 0, 127);
        oacc[qt][1] = __builtin_amdgcn_mfma_scale_f32_16x16x128_f8f6f4(pa.v, vb1.v, oacc[qt][1],
                                                                       0, 0, 0, 127, 0, 127);
        oacc[qt][2] = __builtin_amdgcn_mfma_scale_f32_16x16x128_f8f6f4(pa.v, vb2.v, oacc[qt][2],
                                                                       0, 0, 0, 127, 0, 127);
      }
    }
    BARRIER_LGKM();   // Ps reads drained before next iter rewrites
  }

  // ---- l reduction: lanes l, l^32 share q; wave covers its 32 keys
  {
    float s0 = lsum0 + __shfl_xor(lsum0, 32);
    float s1 = lsum1 + __shfl_xor(lsum1, 32);
    if (hi == 0) { lred[w][ql] = s0; lred[w][ql + 32] = s1; }
  }
  __syncthreads();
  if (t < 64) {
    float s = 0.f;
#pragma unroll
    for (int ww = 0; ww < 16; ++ww) s += lred[ww][t];
    lpart[split * 8192 + qrow0 + t] = s;
  }

  // ---- write unnormalized O partial (bf16); 16x16 C: row=(l>>4)*4+j, col=l&15
#pragma unroll
  for (int qt = 0; qt < 4; ++qt)
#pragma unroll
    for (int nd = 0; nd < 3; ++nd) {
      int col = w * 48 + nd * 16 + l15;
#pragma unroll
      for (int j = 0; j < 4; ++j) {
        int row = qrow0 + qt * 16 + l4g * 4 + j;
        Opart[((size_t)split * 8192 + row) * 768 + col] = f2bf(oacc[qt][nd][j]);
      }
    }
}

// ---------------------------------------------------------------- final combine
__global__ __launch_bounds__(192) void combine(float* __restrict__ out,
                                               const u16* __restrict__ Opart,
                                               const float* __restrict__ lpart,
                                               const float* __restrict__ alpha_p) {
  int row = blockIdx.x, t = threadIdx.x;
  float scale = alpha_p[0] / (lpart[row] + lpart[8192 + row]);
  size_t base = (size_t)row * 768 + t * 4;
  u16x4 o0 = *(const u16x4*)&Opart[base];
  u16x4 o1 = *(const u16x4*)&Opart[(size_t)6291456 + base];
  float4 cur = *(float4*)&out[base];
  union { u32 u; float f; } c0, c1, c2, c3, d0_, d1_, d2_, d3_;
  c0.u = (u32)o0[0] << 16; c1.u = (u32)o0[1] << 16; c2.u = (u32)o0[2] << 16; c3.u = (u32)o0[3] << 16;
  d0_.u = (u32)o1[0] << 16; d1_.u = (u32)o1[1] << 16; d2_.u = (u32)o1[2] << 16; d3_.u = (u32)o1[3] << 16;
  cur.x += (c0.f + d0_.f) * scale;
  cur.y += (c1.f + d1_.f) * scale;
  cur.z += (c2.f + d2_.f) * scale;
  cur.w += (c3.f + d3_.f) * scale;
  *(float4*)&out[base] = cur;
}

// ---------------------------------------------------------------- launch
extern "C" void kernel_launch(void* const* d_in, const int* in_sizes, int n_in,
                              void* d_out, int out_size, void* d_ws, size_t ws_size,
                              hipStream_t stream) {
  const float* x      = (const float*)d_in[0];   // [8192][1024]
  const float* W      = (const float*)d_in[1];   // [768][1024]
  const float* bias   = (const float*)d_in[2];   // [768]
  const float* keys   = (const float*)d_in[3];   // [16384][768]
  const float* values = (const float*)d_in[4];   // [16384][768]
  const float* beta   = (const float*)d_in[5];
  const float* alpha  = (const float*)d_in[6];
  float* out = (float*)d_out;

  char* ws = (char*)d_ws;
  u16* xb    = (u16*)(ws + 0);            // 16,777,216 B
  u16* Wb    = (u16*)(ws + 16777216);     //  1,572,864 B
  u8*  Kf2   = (u8*) (ws + 18350080);     // 12,582,912 B
  u8*  Vtf   = (u8*) (ws + 30932992);     // 12,582,912 B
  u8*  pn8   = (u8*) (ws + 43515904);     //  6,291,456 B
  u16* Opart = (u16*)(ws + 49807360);     // 25,165,824 B
  float* lp  = (float*)(ws + 74973184);   //     65,536 B   (total 75,038,720)

  cvt_bf16<<<2048, 256, 0, stream>>>(x, xb, 8192 * 1024 / 4);
  cvt_bf16<<<768, 256, 0, stream>>>(W, Wb, 768 * 1024 / 4);
  buildK<<<256, 256, 0, stream>>>(keys, Kf2);
  buildV<<<256, 256, 0, stream>>>(values, Vtf);
  gemm1<<<dim3(64, 6), 256, 0, stream>>>(xb, Wb, bias, out);
  rownorm8<<<8192, 384, 0, stream>>>(out, pn8);
  attn<<<dim3(2, 128), 1024, 0, stream>>>(pn8, Kf2, Vtf, beta, Opart, lp);
  combine<<<8192, 192, 0, stream>>>(out, Opart, lp, alpha);
}

// Round 6
// 365.149 us; speedup vs baseline: 1.3645x; 1.3645x over previous
//
#include <hip/hip_runtime.h>
#include <hip/hip_bf16.h>
#include <hip/hip_fp8.h>

typedef unsigned char  u8;
typedef unsigned short u16;
typedef unsigned int   u32;
typedef unsigned long long u64;
typedef __attribute__((ext_vector_type(8)))  short bf16x8;
typedef __attribute__((ext_vector_type(4)))  float f32x4;
typedef __attribute__((ext_vector_type(16))) float f32x16;
typedef __attribute__((ext_vector_type(4)))  u16   u16x4;

__device__ __forceinline__ u16 f2bf(float f) {
  union { float f; u32 u; } v; v.f = f;
  u32 r = v.u + 0x7FFFu + ((v.u >> 16) & 1u);   // RNE
  return (u16)(r >> 16);
}

// pack 2 floats into fp8 e4m3 pair (WORD=false: low 16 bits of old; true: high)
template <bool WORD>
__device__ __forceinline__ u32 pk_fp8(float a, float b, u32 old) {
#if __has_builtin(__builtin_amdgcn_cvt_pk_fp8_f32)
  return (u32)__builtin_amdgcn_cvt_pk_fp8_f32(a, b, (int)old, WORD);
#else
  __hip_fp8_e4m3 x(a), y(b);
  u32 v = (u32)x.__x | ((u32)y.__x << 8);
  return WORD ? ((old & 0xFFFFu) | (v << 16)) : ((old & 0xFFFF0000u) | v);
#endif
}

#define GLL16(gptr, lptr)                                                            \
  __builtin_amdgcn_global_load_lds((const __attribute__((address_space(1))) u32*)(gptr), \
                                   (__attribute__((address_space(3))) u32*)(lptr), 16, 0, 0)

// lgkm-only barrier: does NOT drain vmcnt, so global prefetches stay in flight
#define BARRIER_LGKM() do { asm volatile("s_waitcnt lgkmcnt(0)" ::: "memory"); \
                            __builtin_amdgcn_s_barrier(); } while (0)

// ---------------------------------------------------------------- f32 -> bf16
__global__ __launch_bounds__(256) void cvt_bf16(const float* __restrict__ in,
                                                u16* __restrict__ out, int n4) {
  int i = blockIdx.x * blockDim.x + threadIdx.x;
  int stride = gridDim.x * blockDim.x;
  for (; i < n4; i += stride) {
    float4 v = ((const float4*)in)[i];
    u16x4 o = { f2bf(v.x), f2bf(v.y), f2bf(v.z), f2bf(v.w) };
    ((u16x4*)out)[i] = o;
  }
}

// ------------------- keys [16384][768] f32 -> Kf2 fp8, layout [d8=96][key=16384][8B]
__global__ __launch_bounds__(256) void buildK(const float* __restrict__ in,
                                              u8* __restrict__ out) {
  __shared__ float tile[64][65];
  int kt = blockIdx.x;            // 64 keys per block
  int t = threadIdx.x;
  int r0 = t >> 6, c = t & 63;
  for (int dc = 0; dc < 12; ++dc) {
    if (dc) __syncthreads();
#pragma unroll
    for (int i = 0; i < 16; ++i) {
      int r = i * 4 + r0;
      tile[r][c] = in[(size_t)(kt * 64 + r) * 768 + dc * 64 + c];
    }
    __syncthreads();
    int d8l = t >> 5, kl = t & 31;
#pragma unroll
    for (int j = 0; j < 2; ++j) {
      int key = j * 32 + kl;
      float v0 = tile[key][d8l * 8 + 0], v1 = tile[key][d8l * 8 + 1];
      float v2 = tile[key][d8l * 8 + 2], v3 = tile[key][d8l * 8 + 3];
      float v4 = tile[key][d8l * 8 + 4], v5 = tile[key][d8l * 8 + 5];
      float v6 = tile[key][d8l * 8 + 6], v7 = tile[key][d8l * 8 + 7];
      u32 lo = pk_fp8<false>(v0, v1, 0u); lo = pk_fp8<true>(v2, v3, lo);
      u32 hi = pk_fp8<false>(v4, v5, 0u); hi = pk_fp8<true>(v6, v7, hi);
      uint2 val = { lo, hi };
      *(uint2*)(out + (size_t)(dc * 8 + d8l) * 131072 + (size_t)(kt * 64 + key) * 8) = val;
    }
  }
}

// ------------------- values [16384][768] f32 -> Vtf fp8, layout [k8=2048][d=768][8B]
__global__ __launch_bounds__(256) void buildV(const float* __restrict__ in,
                                              u8* __restrict__ out) {
  __shared__ float tile[64][65];
  int kt = blockIdx.x;            // 64 keys per block
  int t = threadIdx.x;
  int r0 = t >> 6, c = t & 63;
  for (int dc = 0; dc < 12; ++dc) {
    if (dc) __syncthreads();
#pragma unroll
    for (int i = 0; i < 16; ++i) {
      int r = i * 4 + r0;
      tile[r][c] = in[(size_t)(kt * 64 + r) * 768 + dc * 64 + c];
    }
    __syncthreads();
    int sub = t >> 5, dl = t & 31;
#pragma unroll
    for (int j = 0; j < 2; ++j) {
      int d = j * 32 + dl;
      float v0 = tile[sub * 8 + 0][d], v1 = tile[sub * 8 + 1][d];
      float v2 = tile[sub * 8 + 2][d], v3 = tile[sub * 8 + 3][d];
      float v4 = tile[sub * 8 + 4][d], v5 = tile[sub * 8 + 5][d];
      float v6 = tile[sub * 8 + 6][d], v7 = tile[sub * 8 + 7][d];
      u32 lo = pk_fp8<false>(v0, v1, 0u); lo = pk_fp8<true>(v2, v3, lo);
      u32 hi = pk_fp8<false>(v4, v5, 0u); hi = pk_fp8<true>(v6, v7, hi);
      uint2 val = { lo, hi };
      *(uint2*)(out + (size_t)(kt * 8 + sub) * 6144 + (size_t)(dc * 64 + d) * 8) = val;
    }
  }
}

// ---------------------------------------------------------------- GEMM1 (bf16)
__global__ __launch_bounds__(256) void gemm1(const u16* __restrict__ A,
                                             const u16* __restrict__ B,
                                             const float* __restrict__ bias,
                                             float* __restrict__ C) {
  __shared__ u16 As[2][128 * 32];
  __shared__ u16 Bs[2][128 * 32];
  int t = threadIdx.x;
  int brow = blockIdx.x * 128, bcol = blockIdx.y * 128;
  int w = t >> 6, l = t & 63;
  int l15 = l & 15, l4 = l >> 4;
  int wr = (w >> 1) * 64, wc = (w & 1) * 64;
  f32x4 acc[4][4];
#pragma unroll
  for (int i = 0; i < 4; ++i)
#pragma unroll
    for (int j = 0; j < 4; ++j) acc[i][j] = f32x4{0.f, 0.f, 0.f, 0.f};

  auto stage = [&](int buf, int kt) {
#pragma unroll
    for (int i = 0; i < 2; ++i) {
      int id = t + i * 256;
      int row = id >> 2, c = id & 3;
      int cs = (c ^ (row & 3)) * 8;
      GLL16(A + (size_t)(brow + row) * 1024 + kt * 32 + cs, &As[buf][id * 8]);
      GLL16(B + (size_t)(bcol + row) * 1024 + kt * 32 + cs, &Bs[buf][id * 8]);
    }
  };
  stage(0, 0);
  for (int kt = 0; kt < 32; ++kt) {
    int buf = kt & 1;
    __syncthreads();
    if (kt < 31) stage(buf ^ 1, kt + 1);
    bf16x8 a[4], b[4];
#pragma unroll
    for (int mf = 0; mf < 4; ++mf) {
      int row = wr + mf * 16 + l15;
      a[mf] = *(const bf16x8*)&As[buf][row * 32 + ((l4 ^ (row & 3)) * 8)];
    }
#pragma unroll
    for (int nf = 0; nf < 4; ++nf) {
      int row = wc + nf * 16 + l15;
      b[nf] = *(const bf16x8*)&Bs[buf][row * 32 + ((l4 ^ (row & 3)) * 8)];
    }
#pragma unroll
    for (int mf = 0; mf < 4; ++mf)
#pragma unroll
      for (int nf = 0; nf < 4; ++nf)
        acc[mf][nf] = __builtin_amdgcn_mfma_f32_16x16x32_bf16(a[mf], b[nf], acc[mf][nf], 0, 0, 0);
  }
#pragma unroll
  for (int mf = 0; mf < 4; ++mf)
#pragma unroll
    for (int nf = 0; nf < 4; ++nf) {
      int col = bcol + wc + nf * 16 + l15;
      float bv = bias[col];
#pragma unroll
      for (int j = 0; j < 4; ++j) {
        int row = brow + wr + mf * 16 + l4 * 4 + j;
        C[(size_t)row * 768 + col] = acc[mf][nf][j] + bv;
      }
    }
}

// ---------------------------------------------------------------- row L2-normalize -> fp8
__global__ __launch_bounds__(384) void rownorm8(const float* __restrict__ P,
                                                u8* __restrict__ pn8) {
  int row = blockIdx.x, t = threadIdx.x;
  size_t base = (size_t)row * 768;
  float2 v = *(const float2*)&P[base + 2 * t];
  float ss = v.x * v.x + v.y * v.y;
#pragma unroll
  for (int o = 32; o; o >>= 1) ss += __shfl_xor(ss, o);
  __shared__ float wsum[6];
  if ((t & 63) == 0) wsum[t >> 6] = ss;
  __syncthreads();
  float tot = wsum[0] + wsum[1] + wsum[2] + wsum[3] + wsum[4] + wsum[5];
  float inv = 1.0f / fmaxf(sqrtf(tot), 1e-12f);
  u32 pk = pk_fp8<false>(v.x * inv, v.y * inv, 0u);
  *(u16*)(pn8 + base + 2 * t) = (u16)(pk & 0xFFFFu);
}

// ---------------------------------------------------------------- fused attention, fp8
// 16 waves (1024 thr), BM=64 q, KVBLK=512 (32 keys/wave QK), nsplit=2, d-slice 48/wave PV.
// Round-6 schedule: Ps double-buffered -> ONE lgkm-only barrier per iter; next-tile K
// prefetch issued before the barrier (stays in flight, vmcnt not drained); setprio
// around MFMA clusters.
__global__ __launch_bounds__(1024, 4) void attn(const u8* __restrict__ pn8,
                                                const u8* __restrict__ Kf2,
                                                const u8* __restrict__ Vtf,
                                                const float* __restrict__ beta_p,
                                                u16* __restrict__ Opart,
                                                float* __restrict__ lpart) {
  __shared__ long Qlds[96 * 64];     // 48 KB [c8][q]
  __shared__ long Ps[2][64 * 64];    // 2 x 32 KB [kc8][q]
  __shared__ float lred[16][64];     // 4 KB
  int t = threadIdx.x;
  int w = t >> 6, l = t & 63;
  int ql = l & 31, hi = l >> 5;        // 32x32 lanes
  int l15 = l & 15, l4g = l >> 4;      // 16x16 lanes (0..3)
  int split = blockIdx.x, qb = blockIdx.y;
  int qrow0 = qb * 64;
  float blog2e = beta_p[0] * 1.44269504089f;

  // ---- stage Q [64 q][768 d] fp8 into [c8][q] (once)
#pragma unroll
  for (int i = 0; i < 6; ++i) {
    int id = i * 1024 + t;
    int c8 = id >> 6, q = id & 63;
    Qlds[c8 * 64 + q] = *(const long*)(pn8 + (size_t)(qrow0 + q) * 768 + (size_t)c8 * 8);
  }

  f32x4 oacc[4][3];
#pragma unroll
  for (int mq = 0; mq < 4; ++mq)
#pragma unroll
    for (int nd = 0; nd < 3; ++nd) oacc[mq][nd] = f32x4{0.f, 0.f, 0.f, 0.f};
  float lsum0 = 0.f, lsum1 = 0.f;

  int kbase = split * 8192;
  const long* Kp = (const long*)Kf2 + (size_t)hi * 16384 + (size_t)(kbase + w * 32 + ql);
  const long* Vp = (const long*)Vtf + ((size_t)(kbase >> 3) + l4g) * 768 + (size_t)(w * 48 + l15);

  // preload K for tile 0 (in flight across the staging barrier)
  long kbuf[6];
#pragma unroll
  for (int i = 0; i < 6; ++i) kbuf[i] = Kp[(size_t)i * 32768];

  __syncthreads();

  for (int it = 0; it < 16; ++it) {
    int n0 = it * 512;
    const long* kp = Kp + n0;
    long* psb = &Ps[it & 1][0];

    // ---------- QK^T: wave w -> keys [n0+w*32,+32), all 64 q
    f32x16 sacc0 = (f32x16)0.0f;
    f32x16 sacc1 = (f32x16)0.0f;
    __builtin_amdgcn_s_setprio(1);
#pragma unroll
    for (int ks = 0; ks < 48; ++ks) {
      long kv = kbuf[ks % 6];
      if (ks < 42) kbuf[ks % 6] = kp[(size_t)(ks + 6) * 32768];
      long q0 = Qlds[(ks * 2 + hi) * 64 + ql];
      long q1 = Qlds[(ks * 2 + hi) * 64 + ql + 32];
      sacc0 = __builtin_amdgcn_mfma_f32_32x32x16_fp8_fp8(kv, q0, sacc0, 0, 0, 0);
      sacc1 = __builtin_amdgcn_mfma_f32_32x32x16_fp8_fp8(kv, q1, sacc1, 0, 0, 0);
    }
    __builtin_amdgcn_s_setprio(0);

    // ---------- exp (no max), lsum, pack fp8 -> Ps[it&1] [kc8][q]
    // sacc reg r: key-in-wave = (r&3) + 8*(r>>2) + 4*hi ; q = ql (+32 for sacc1)
#pragma unroll
    for (int qf = 0; qf < 2; ++qf) {
      int q = ql + qf * 32;
      float lacc = 0.f;
#pragma unroll
      for (int rg = 0; rg < 4; ++rg) {
        float p0, p1, p2, p3;
        if (qf == 0) {
          p0 = exp2f(blog2e * sacc0[rg * 4 + 0]); p1 = exp2f(blog2e * sacc0[rg * 4 + 1]);
          p2 = exp2f(blog2e * sacc0[rg * 4 + 2]); p3 = exp2f(blog2e * sacc0[rg * 4 + 3]);
        } else {
          p0 = exp2f(blog2e * sacc1[rg * 4 + 0]); p1 = exp2f(blog2e * sacc1[rg * 4 + 1]);
          p2 = exp2f(blog2e * sacc1[rg * 4 + 2]); p3 = exp2f(blog2e * sacc1[rg * 4 + 3]);
        }
        lacc += (p0 + p1) + (p2 + p3);
        u32 pk = pk_fp8<false>(p0, p1, 0u); pk = pk_fp8<true>(p2, p3, pk);
        ((u32*)psb)[(w * 4 + rg) * 128 + q * 2 + hi] = pk;
      }
      if (qf == 0) lsum0 += lacc; else lsum1 += lacc;
    }

    // ---------- prefetch K for next tile (stays in flight across barrier)
    if (it < 15) {
      const long* kpn = Kp + (size_t)(it + 1) * 512;
#pragma unroll
      for (int i = 0; i < 6; ++i) kbuf[i] = kpn[(size_t)i * 32768];
    }

    BARRIER_LGKM();   // P(it) visible to all waves; kbuf loads NOT drained

    // ---------- PV: O[64 q][48 d per wave] += P * V  (16x16x32)
    long vbuf[2][3];
#pragma unroll
    for (int kc = 0; kc < 2; ++kc)
#pragma unroll
      for (int nd = 0; nd < 3; ++nd)
        vbuf[kc][nd] = Vp[((size_t)(n0 >> 3) + kc * 4) * 768 + nd * 16];
    __builtin_amdgcn_s_setprio(1);
#pragma unroll
    for (int kc = 0; kc < 16; ++kc) {
      long v0 = vbuf[kc & 1][0], v1 = vbuf[kc & 1][1], v2 = vbuf[kc & 1][2];
      if (kc < 14) {
#pragma unroll
        for (int nd = 0; nd < 3; ++nd)
          vbuf[kc & 1][nd] = Vp[((size_t)(n0 >> 3) + (kc + 2) * 4) * 768 + nd * 16];
      }
#pragma unroll
      for (int mq = 0; mq < 4; ++mq) {
        long pa = psb[(kc * 4 + l4g) * 64 + mq * 16 + l15];
        oacc[mq][0] = __builtin_amdgcn_mfma_f32_16x16x32_fp8_fp8(pa, v0, oacc[mq][0], 0, 0, 0);
        oacc[mq][1] = __builtin_amdgcn_mfma_f32_16x16x32_fp8_fp8(pa, v1, oacc[mq][1], 0, 0, 0);
        oacc[mq][2] = __builtin_amdgcn_mfma_f32_16x16x32_fp8_fp8(pa, v2, oacc[mq][2], 0, 0, 0);
      }
    }
    __builtin_amdgcn_s_setprio(0);
    // no second barrier: Ps is double-buffered; next iter writes Ps[(it+1)&1],
    // and any rewrite of Ps[it&1] happens only after the NEXT barrier.
  }

  // ---- l reduction: lanes l, l^32 share q; wave covers its 32 keys
  {
    float s0 = lsum0 + __shfl_xor(lsum0, 32);
    float s1 = lsum1 + __shfl_xor(lsum1, 32);
    if (hi == 0) { lred[w][ql] = s0; lred[w][ql + 32] = s1; }
  }
  __syncthreads();
  if (t < 64) {
    float s = 0.f;
#pragma unroll
    for (int ww = 0; ww < 16; ++ww) s += lred[ww][t];
    lpart[split * 8192 + qrow0 + t] = s;
  }

  // ---- write unnormalized O partial (bf16); 16x16 C: row=(l>>4)*4+j, col=l&15
#pragma unroll
  for (int mq = 0; mq < 4; ++mq)
#pragma unroll
    for (int nd = 0; nd < 3; ++nd) {
      int col = w * 48 + nd * 16 + l15;
#pragma unroll
      for (int j = 0; j < 4; ++j) {
        int row = qrow0 + mq * 16 + l4g * 4 + j;
        Opart[((size_t)split * 8192 + row) * 768 + col] = f2bf(oacc[mq][nd][j]);
      }
    }
}

// ---------------------------------------------------------------- final combine
__global__ __launch_bounds__(192) void combine(float* __restrict__ out,
                                               const u16* __restrict__ Opart,
                                               const float* __restrict__ lpart,
                                               const float* __restrict__ alpha_p) {
  int row = blockIdx.x, t = threadIdx.x;
  float scale = alpha_p[0] / (lpart[row] + lpart[8192 + row]);
  size_t base = (size_t)row * 768 + t * 4;
  u16x4 o0 = *(const u16x4*)&Opart[base];
  u16x4 o1 = *(const u16x4*)&Opart[(size_t)6291456 + base];
  float4 cur = *(float4*)&out[base];
  union { u32 u; float f; } c0, c1, c2, c3, d0_, d1_, d2_, d3_;
  c0.u = (u32)o0[0] << 16; c1.u = (u32)o0[1] << 16; c2.u = (u32)o0[2] << 16; c3.u = (u32)o0[3] << 16;
  d0_.u = (u32)o1[0] << 16; d1_.u = (u32)o1[1] << 16; d2_.u = (u32)o1[2] << 16; d3_.u = (u32)o1[3] << 16;
  cur.x += (c0.f + d0_.f) * scale;
  cur.y += (c1.f + d1_.f) * scale;
  cur.z += (c2.f + d2_.f) * scale;
  cur.w += (c3.f + d3_.f) * scale;
  *(float4*)&out[base] = cur;
}

// ---------------------------------------------------------------- launch
extern "C" void kernel_launch(void* const* d_in, const int* in_sizes, int n_in,
                              void* d_out, int out_size, void* d_ws, size_t ws_size,
                              hipStream_t stream) {
  const float* x      = (const float*)d_in[0];   // [8192][1024]
  const float* W      = (const float*)d_in[1];   // [768][1024]
  const float* bias   = (const float*)d_in[2];   // [768]
  const float* keys   = (const float*)d_in[3];   // [16384][768]
  const float* values = (const float*)d_in[4];   // [16384][768]
  const float* beta   = (const float*)d_in[5];
  const float* alpha  = (const float*)d_in[6];
  float* out = (float*)d_out;

  char* ws = (char*)d_ws;
  u16* xb    = (u16*)(ws + 0);            // 16,777,216 B
  u16* Wb    = (u16*)(ws + 16777216);     //  1,572,864 B
  u8*  Kf2   = (u8*) (ws + 18350080);     // 12,582,912 B
  u8*  Vtf   = (u8*) (ws + 30932992);     // 12,582,912 B
  u8*  pn8   = (u8*) (ws + 43515904);     //  6,291,456 B
  u16* Opart = (u16*)(ws + 49807360);     // 25,165,824 B
  float* lp  = (float*)(ws + 74973184);   //     65,536 B   (total 75,038,720)

  cvt_bf16<<<2048, 256, 0, stream>>>(x, xb, 8192 * 1024 / 4);
  cvt_bf16<<<768, 256, 0, stream>>>(W, Wb, 768 * 1024 / 4);
  buildK<<<256, 256, 0, stream>>>(keys, Kf2);
  buildV<<<256, 256, 0, stream>>>(values, Vtf);
  gemm1<<<dim3(64, 6), 256, 0, stream>>>(xb, Wb, bias, out);
  rownorm8<<<8192, 384, 0, stream>>>(out, pn8);
  attn<<<dim3(2, 128), 1024, 0, stream>>>(pn8, Kf2, Vtf, beta, Opart, lp);
  combine<<<8192, 192, 0, stream>>>(out, Opart, lp, alpha);
}

// Round 7
// 324.507 us; speedup vs baseline: 1.5353x; 1.1252x over previous
//
#include <hip/hip_runtime.h>
#include <hip/hip_bf16.h>
#include <hip/hip_fp8.h>

typedef unsigned char  u8;
typedef unsigned short u16;
typedef unsigned int   u32;
typedef __attribute__((ext_vector_type(8)))  short bf16x8;
typedef __attribute__((ext_vector_type(4)))  float f32x4;
typedef __attribute__((ext_vector_type(4)))  int   i32x4;
typedef __attribute__((ext_vector_type(16))) int   i32x16;
typedef __attribute__((ext_vector_type(4)))  u16   u16x4;

__device__ __forceinline__ u16 f2bf(float f) {
  union { float f; u32 u; } v; v.f = f;
  u32 r = v.u + 0x7FFFu + ((v.u >> 16) & 1u);   // RNE
  return (u16)(r >> 16);
}
__device__ __forceinline__ int q127(float x) { return (int)rintf(x * 127.0f); }

#define GLL16(gptr, lptr)                                                            \
  __builtin_amdgcn_global_load_lds((const __attribute__((address_space(1))) u32*)(gptr), \
                                   (__attribute__((address_space(3))) u32*)(lptr), 16, 0, 0)

// lgkm-only barrier: does NOT drain vmcnt, so global prefetches stay in flight
#define BARRIER_LGKM() do { asm volatile("s_waitcnt lgkmcnt(0)" ::: "memory"); \
                            __builtin_amdgcn_s_barrier(); } while (0)

// ---------------------------------------------------------------- f32 -> bf16
__global__ __launch_bounds__(256) void cvt_bf16(const float* __restrict__ in,
                                                u16* __restrict__ out, int n4) {
  int i = blockIdx.x * blockDim.x + threadIdx.x;
  int stride = gridDim.x * blockDim.x;
  for (; i < n4; i += stride) {
    float4 v = ((const float4*)in)[i];
    u16x4 o = { f2bf(v.x), f2bf(v.y), f2bf(v.z), f2bf(v.w) };
    ((u16x4*)out)[i] = o;
  }
}

// ------------------- keys [16384][768] f32 -> Ki8, layout [d8=96][key=16384][8B] i8
__global__ __launch_bounds__(256) void buildK(const float* __restrict__ in,
                                              u8* __restrict__ out) {
  __shared__ float tile[64][65];
  int kt = blockIdx.x;            // 64 keys per block
  int t = threadIdx.x;
  int r0 = t >> 6, c = t & 63;
  for (int dc = 0; dc < 12; ++dc) {
    if (dc) __syncthreads();
#pragma unroll
    for (int i = 0; i < 16; ++i) {
      int r = i * 4 + r0;
      tile[r][c] = in[(size_t)(kt * 64 + r) * 768 + dc * 64 + c];
    }
    __syncthreads();
    int d8l = t >> 5, kl = t & 31;
#pragma unroll
    for (int j = 0; j < 2; ++j) {
      int key = j * 32 + kl;
      int s0 = q127(tile[key][d8l * 8 + 0]), s1 = q127(tile[key][d8l * 8 + 1]);
      int s2 = q127(tile[key][d8l * 8 + 2]), s3 = q127(tile[key][d8l * 8 + 3]);
      int s4 = q127(tile[key][d8l * 8 + 4]), s5 = q127(tile[key][d8l * 8 + 5]);
      int s6 = q127(tile[key][d8l * 8 + 6]), s7 = q127(tile[key][d8l * 8 + 7]);
      u32 lo = (s0 & 255) | ((s1 & 255) << 8) | ((s2 & 255) << 16) | ((u32)(s3 & 255) << 24);
      u32 hi = (s4 & 255) | ((s5 & 255) << 8) | ((s6 & 255) << 16) | ((u32)(s7 & 255) << 24);
      uint2 val = { lo, hi };
      *(uint2*)(out + (size_t)(dc * 8 + d8l) * 131072 + (size_t)(kt * 64 + key) * 8) = val;
    }
  }
}

// ------------------- values [16384][768] f32 -> Vi8, layout [k8=2048][d=768][8B] i8
__global__ __launch_bounds__(256) void buildV(const float* __restrict__ in,
                                              u8* __restrict__ out) {
  __shared__ float tile[64][65];
  int kt = blockIdx.x;            // 64 keys per block
  int t = threadIdx.x;
  int r0 = t >> 6, c = t & 63;
  for (int dc = 0; dc < 12; ++dc) {
    if (dc) __syncthreads();
#pragma unroll
    for (int i = 0; i < 16; ++i) {
      int r = i * 4 + r0;
      tile[r][c] = in[(size_t)(kt * 64 + r) * 768 + dc * 64 + c];
    }
    __syncthreads();
    int sub = t >> 5, dl = t & 31;
#pragma unroll
    for (int j = 0; j < 2; ++j) {
      int d = j * 32 + dl;
      int s0 = q127(tile[sub * 8 + 0][d]), s1 = q127(tile[sub * 8 + 1][d]);
      int s2 = q127(tile[sub * 8 + 2][d]), s3 = q127(tile[sub * 8 + 3][d]);
      int s4 = q127(tile[sub * 8 + 4][d]), s5 = q127(tile[sub * 8 + 5][d]);
      int s6 = q127(tile[sub * 8 + 6][d]), s7 = q127(tile[sub * 8 + 7][d]);
      u32 lo = (s0 & 255) | ((s1 & 255) << 8) | ((s2 & 255) << 16) | ((u32)(s3 & 255) << 24);
      u32 hi = (s4 & 255) | ((s5 & 255) << 8) | ((s6 & 255) << 16) | ((u32)(s7 & 255) << 24);
      uint2 val = { lo, hi };
      *(uint2*)(out + (size_t)(kt * 8 + sub) * 6144 + (size_t)(dc * 64 + d) * 8) = val;
    }
  }
}

// ---------------------------------------------------------------- GEMM1 (bf16)
__global__ __launch_bounds__(256) void gemm1(const u16* __restrict__ A,
                                             const u16* __restrict__ B,
                                             const float* __restrict__ bias,
                                             float* __restrict__ C) {
  __shared__ u16 As[2][128 * 32];
  __shared__ u16 Bs[2][128 * 32];
  int t = threadIdx.x;
  int brow = blockIdx.x * 128, bcol = blockIdx.y * 128;
  int w = t >> 6, l = t & 63;
  int l15 = l & 15, l4 = l >> 4;
  int wr = (w >> 1) * 64, wc = (w & 1) * 64;
  f32x4 acc[4][4];
#pragma unroll
  for (int i = 0; i < 4; ++i)
#pragma unroll
    for (int j = 0; j < 4; ++j) acc[i][j] = f32x4{0.f, 0.f, 0.f, 0.f};

  auto stage = [&](int buf, int kt) {
#pragma unroll
    for (int i = 0; i < 2; ++i) {
      int id = t + i * 256;
      int row = id >> 2, c = id & 3;
      int cs = (c ^ (row & 3)) * 8;
      GLL16(A + (size_t)(brow + row) * 1024 + kt * 32 + cs, &As[buf][id * 8]);
      GLL16(B + (size_t)(bcol + row) * 1024 + kt * 32 + cs, &Bs[buf][id * 8]);
    }
  };
  stage(0, 0);
  for (int kt = 0; kt < 32; ++kt) {
    int buf = kt & 1;
    __syncthreads();
    if (kt < 31) stage(buf ^ 1, kt + 1);
    bf16x8 a[4], b[4];
#pragma unroll
    for (int mf = 0; mf < 4; ++mf) {
      int row = wr + mf * 16 + l15;
      a[mf] = *(const bf16x8*)&As[buf][row * 32 + ((l4 ^ (row & 3)) * 8)];
    }
#pragma unroll
    for (int nf = 0; nf < 4; ++nf) {
      int row = wc + nf * 16 + l15;
      b[nf] = *(const bf16x8*)&Bs[buf][row * 32 + ((l4 ^ (row & 3)) * 8)];
    }
#pragma unroll
    for (int mf = 0; mf < 4; ++mf)
#pragma unroll
      for (int nf = 0; nf < 4; ++nf)
        acc[mf][nf] = __builtin_amdgcn_mfma_f32_16x16x32_bf16(a[mf], b[nf], acc[mf][nf], 0, 0, 0);
  }
#pragma unroll
  for (int mf = 0; mf < 4; ++mf)
#pragma unroll
    for (int nf = 0; nf < 4; ++nf) {
      int col = bcol + wc + nf * 16 + l15;
      float bv = bias[col];
#pragma unroll
      for (int j = 0; j < 4; ++j) {
        int row = brow + wr + mf * 16 + l4 * 4 + j;
        C[(size_t)row * 768 + col] = acc[mf][nf][j] + bv;
      }
    }
}

// ---------------------------------------------------------------- row L2-normalize -> i8
__global__ __launch_bounds__(384) void rownorm8(const float* __restrict__ P,
                                                u8* __restrict__ q8) {
  int row = blockIdx.x, t = threadIdx.x;
  size_t base = (size_t)row * 768;
  float2 v = *(const float2*)&P[base + 2 * t];
  float ss = v.x * v.x + v.y * v.y;
#pragma unroll
  for (int o = 32; o; o >>= 1) ss += __shfl_xor(ss, o);
  __shared__ float wsum[6];
  if ((t & 63) == 0) wsum[t >> 6] = ss;
  __syncthreads();
  float tot = wsum[0] + wsum[1] + wsum[2] + wsum[3] + wsum[4] + wsum[5];
  float inv = 1.0f / fmaxf(sqrtf(tot), 1e-12f);
  int a = q127(v.x * inv), b = q127(v.y * inv);
  *(u16*)(q8 + base + 2 * t) = (u16)((a & 255) | ((b & 255) << 8));
}

// ---------------------------------------------------------------- fused attention, i8
// 16 waves (1024 thr), BM=64 q, KVBLK=512 (32 keys/wave QK), nsplit=2, d-slice 48/wave PV.
// QK: mfma_i32_32x32x32_i8 (swapped, A=K global, B=Q LDS) -> S^T int32; logit = s*beta/127^2.
// PV: mfma_i32_16x16x64_i8, P quantized i8 at scale 127/e^beta (clamped), V i8 at 127.
// Same schedule as round 6: Ps double-buffered, one lgkm-only barrier/iter, in-flight
// K prefetch across the barrier, setprio around MFMA clusters.
__global__ __launch_bounds__(1024, 4) void attn(const u8* __restrict__ q8,
                                                const u8* __restrict__ Ki8,
                                                const u8* __restrict__ Vi8,
                                                const float* __restrict__ beta_p,
                                                u16* __restrict__ Opart,
                                                float* __restrict__ lpart) {
  __shared__ long Qlds[96 * 64];     // 48 KB [c8][q] (i8 payload)
  __shared__ long Ps[2][64 * 64];    // 2 x 32 KB [kc8][q] (i8 payload)
  __shared__ float lred[16][64];     // 4 KB
  int t = threadIdx.x;
  int w = t >> 6, l = t & 63;
  int ql = l & 31, hi = l >> 5;        // 32x32 lanes
  int l15 = l & 15, l4g = l >> 4;      // 16x16 lanes (0..3)
  int split = blockIdx.x, qb = blockIdx.y;
  int qrow0 = qb * 64;
  float beta = beta_p[0];
  float c1 = beta * 1.44269504089f / 16129.0f;   // int logit -> log2 domain
  float pscale = 127.0f / expf(beta);            // P -> i8
  float ovs = expf(beta) / 16129.0f;             // i32 PV acc -> float (P,V both /127)

  // ---- stage Q [64 q][768 d] i8 into [c8][q] (once)
#pragma unroll
  for (int i = 0; i < 6; ++i) {
    int id = i * 1024 + t;
    int c8 = id >> 6, q = id & 63;
    Qlds[c8 * 64 + q] = *(const long*)(q8 + (size_t)(qrow0 + q) * 768 + (size_t)c8 * 8);
  }

  i32x4 oacc[4][3];
#pragma unroll
  for (int mq = 0; mq < 4; ++mq)
#pragma unroll
    for (int nd = 0; nd < 3; ++nd) oacc[mq][nd] = i32x4{0, 0, 0, 0};
  float lsum0 = 0.f, lsum1 = 0.f;

  int kbase = split * 8192;
  // K: per step ks lane provides d8 chunks (4ks+2hi), (4ks+2hi+1); fold 2hi into base
  const long* Kp = (const long*)Ki8 + (size_t)(2 * hi) * 16384 + (size_t)(kbase + w * 32 + ql);
  // V: per kstep lane provides k8 chunks (8ks+2l4g), (+1); fold 2l4g into base
  const long* Vp = (const long*)Vi8 + ((size_t)(kbase >> 3) + 2 * l4g) * 768 + (size_t)(w * 48 + l15);

  // preload K for tile 0 (3-step lookahead, in flight across the staging barrier)
  long kb[3][2];
#pragma unroll
  for (int s = 0; s < 3; ++s) {
    kb[s][0] = Kp[(size_t)(4 * s) * 16384];
    kb[s][1] = Kp[(size_t)(4 * s + 1) * 16384];
  }

  __syncthreads();

  for (int it = 0; it < 16; ++it) {
    int n0 = it * 512;
    const long* kp = Kp + n0;
    long* psb = &Ps[it & 1][0];

    // ---------- QK^T: wave w -> keys [n0+w*32,+32), all 64 q; 24 steps of K=32
    i32x16 sacc0 = (i32x16)0;
    i32x16 sacc1 = (i32x16)0;
    __builtin_amdgcn_s_setprio(1);
#pragma unroll
    for (int ks = 0; ks < 24; ++ks) {
      union { long l[2]; i32x4 v; } av, q0u, q1u;
      av.l[0] = kb[ks % 3][0];
      av.l[1] = kb[ks % 3][1];
      if (ks < 21) {
        kb[ks % 3][0] = kp[(size_t)(4 * (ks + 3)) * 16384];
        kb[ks % 3][1] = kp[(size_t)(4 * (ks + 3) + 1) * 16384];
      }
      q0u.l[0] = Qlds[(4 * ks + 2 * hi) * 64 + ql];
      q0u.l[1] = Qlds[(4 * ks + 2 * hi + 1) * 64 + ql];
      q1u.l[0] = Qlds[(4 * ks + 2 * hi) * 64 + ql + 32];
      q1u.l[1] = Qlds[(4 * ks + 2 * hi + 1) * 64 + ql + 32];
      sacc0 = __builtin_amdgcn_mfma_i32_32x32x32_i8(av.v, q0u.v, sacc0, 0, 0, 0);
      sacc1 = __builtin_amdgcn_mfma_i32_32x32x32_i8(av.v, q1u.v, sacc1, 0, 0, 0);
    }
    __builtin_amdgcn_s_setprio(0);

    // ---------- exp (no max), lsum, quantize P -> i8 -> Ps[it&1] [kc8][q]
    // sacc reg r: key-in-wave = (r&3) + 8*(r>>2) + 4*hi ; q = ql (+32 for sacc1)
#pragma unroll
    for (int qf = 0; qf < 2; ++qf) {
      int q = ql + qf * 32;
      float lacc = 0.f;
#pragma unroll
      for (int rg = 0; rg < 4; ++rg) {
        float p0, p1, p2, p3;
        if (qf == 0) {
          p0 = exp2f(c1 * (float)sacc0[rg * 4 + 0]); p1 = exp2f(c1 * (float)sacc0[rg * 4 + 1]);
          p2 = exp2f(c1 * (float)sacc0[rg * 4 + 2]); p3 = exp2f(c1 * (float)sacc0[rg * 4 + 3]);
        } else {
          p0 = exp2f(c1 * (float)sacc1[rg * 4 + 0]); p1 = exp2f(c1 * (float)sacc1[rg * 4 + 1]);
          p2 = exp2f(c1 * (float)sacc1[rg * 4 + 2]); p3 = exp2f(c1 * (float)sacc1[rg * 4 + 3]);
        }
        lacc += (p0 + p1) + (p2 + p3);
        int i0 = (int)rintf(fminf(p0 * pscale, 127.f));
        int i1 = (int)rintf(fminf(p1 * pscale, 127.f));
        int i2 = (int)rintf(fminf(p2 * pscale, 127.f));
        int i3 = (int)rintf(fminf(p3 * pscale, 127.f));
        u32 pk = (u32)i0 | ((u32)i1 << 8) | ((u32)i2 << 16) | ((u32)i3 << 24);
        ((u32*)psb)[(w * 4 + rg) * 128 + q * 2 + hi] = pk;
      }
      if (qf == 0) lsum0 += lacc; else lsum1 += lacc;
    }

    // ---------- prefetch K for next tile (stays in flight across barrier)
    if (it < 15) {
      const long* kpn = Kp + (size_t)(it + 1) * 512;
#pragma unroll
      for (int s = 0; s < 3; ++s) {
        kb[s][0] = kpn[(size_t)(4 * s) * 16384];
        kb[s][1] = kpn[(size_t)(4 * s + 1) * 16384];
      }
    }
    // ---------- preload V for kstep 0 (no Ps dependency -> before barrier)
    long vb[2][3][2];
#pragma unroll
    for (int nd = 0; nd < 3; ++nd) {
      size_t off = (size_t)(n0 >> 3) * 768 + nd * 16;
      vb[0][nd][0] = Vp[off];
      vb[0][nd][1] = Vp[off + 768];
    }

    BARRIER_LGKM();   // P(it) visible to all waves; kb/vb loads NOT drained

    // ---------- PV: O[64 q][48 d per wave] += P * V  (16x16x64 i8, 8 ksteps)
    __builtin_amdgcn_s_setprio(1);
#pragma unroll
    for (int ksv = 0; ksv < 8; ++ksv) {
      int cur = ksv & 1;
      if (ksv < 7) {
#pragma unroll
        for (int nd = 0; nd < 3; ++nd) {
          size_t off = ((size_t)(n0 >> 3) + (ksv + 1) * 8) * 768 + nd * 16;
          vb[cur ^ 1][nd][0] = Vp[off];
          vb[cur ^ 1][nd][1] = Vp[off + 768];
        }
      }
      union { long l[2]; i32x4 v; } v0, v1, v2;
      v0.l[0] = vb[cur][0][0]; v0.l[1] = vb[cur][0][1];
      v1.l[0] = vb[cur][1][0]; v1.l[1] = vb[cur][1][1];
      v2.l[0] = vb[cur][2][0]; v2.l[1] = vb[cur][2][1];
#pragma unroll
      for (int mq = 0; mq < 4; ++mq) {
        union { long l[2]; i32x4 v; } pa;
        pa.l[0] = psb[(8 * ksv + 2 * l4g) * 64 + mq * 16 + l15];
        pa.l[1] = psb[(8 * ksv + 2 * l4g + 1) * 64 + mq * 16 + l15];
        oacc[mq][0] = __builtin_amdgcn_mfma_i32_16x16x64_i8(pa.v, v0.v, oacc[mq][0], 0, 0, 0);
        oacc[mq][1] = __builtin_amdgcn_mfma_i32_16x16x64_i8(pa.v, v1.v, oacc[mq][1], 0, 0, 0);
        oacc[mq][2] = __builtin_amdgcn_mfma_i32_16x16x64_i8(pa.v, v2.v, oacc[mq][2], 0, 0, 0);
      }
    }
    __builtin_amdgcn_s_setprio(0);
    // no second barrier: Ps double-buffered; rewrite of Ps[it&1] is after the NEXT barrier
  }

  // ---- l reduction: lanes l, l^32 share q; wave covers its 32 keys
  {
    float s0 = lsum0 + __shfl_xor(lsum0, 32);
    float s1 = lsum1 + __shfl_xor(lsum1, 32);
    if (hi == 0) { lred[w][ql] = s0; lred[w][ql + 32] = s1; }
  }
  __syncthreads();
  if (t < 64) {
    float s = 0.f;
#pragma unroll
    for (int ww = 0; ww < 16; ++ww) s += lred[ww][t];
    lpart[split * 8192 + qrow0 + t] = s;
  }

  // ---- write unnormalized O partial (bf16); 16x16 C: row=(l>>4)*4+j, col=l&15
#pragma unroll
  for (int mq = 0; mq < 4; ++mq)
#pragma unroll
    for (int nd = 0; nd < 3; ++nd) {
      int col = w * 48 + nd * 16 + l15;
#pragma unroll
      for (int j = 0; j < 4; ++j) {
        int row = qrow0 + mq * 16 + l4g * 4 + j;
        Opart[((size_t)split * 8192 + row) * 768 + col] = f2bf((float)oacc[mq][nd][j] * ovs);
      }
    }
}

// ---------------------------------------------------------------- final combine
__global__ __launch_bounds__(192) void combine(float* __restrict__ out,
                                               const u16* __restrict__ Opart,
                                               const float* __restrict__ lpart,
                                               const float* __restrict__ alpha_p) {
  int row = blockIdx.x, t = threadIdx.x;
  float scale = alpha_p[0] / (lpart[row] + lpart[8192 + row]);
  size_t base = (size_t)row * 768 + t * 4;
  u16x4 o0 = *(const u16x4*)&Opart[base];
  u16x4 o1 = *(const u16x4*)&Opart[(size_t)6291456 + base];
  float4 cur = *(float4*)&out[base];
  union { u32 u; float f; } c0, c1, c2, c3, d0_, d1_, d2_, d3_;
  c0.u = (u32)o0[0] << 16; c1.u = (u32)o0[1] << 16; c2.u = (u32)o0[2] << 16; c3.u = (u32)o0[3] << 16;
  d0_.u = (u32)o1[0] << 16; d1_.u = (u32)o1[1] << 16; d2_.u = (u32)o1[2] << 16; d3_.u = (u32)o1[3] << 16;
  cur.x += (c0.f + d0_.f) * scale;
  cur.y += (c1.f + d1_.f) * scale;
  cur.z += (c2.f + d2_.f) * scale;
  cur.w += (c3.f + d3_.f) * scale;
  *(float4*)&out[base] = cur;
}

// ---------------------------------------------------------------- launch
extern "C" void kernel_launch(void* const* d_in, const int* in_sizes, int n_in,
                              void* d_out, int out_size, void* d_ws, size_t ws_size,
                              hipStream_t stream) {
  const float* x      = (const float*)d_in[0];   // [8192][1024]
  const float* W      = (const float*)d_in[1];   // [768][1024]
  const float* bias   = (const float*)d_in[2];   // [768]
  const float* keys   = (const float*)d_in[3];   // [16384][768]
  const float* values = (const float*)d_in[4];   // [16384][768]
  const float* beta   = (const float*)d_in[5];
  const float* alpha  = (const float*)d_in[6];
  float* out = (float*)d_out;

  char* ws = (char*)d_ws;
  u16* xb    = (u16*)(ws + 0);            // 16,777,216 B
  u16* Wb    = (u16*)(ws + 16777216);     //  1,572,864 B
  u8*  Ki8   = (u8*) (ws + 18350080);     // 12,582,912 B
  u8*  Vi8   = (u8*) (ws + 30932992);     // 12,582,912 B
  u8*  q8    = (u8*) (ws + 43515904);     //  6,291,456 B
  u16* Opart = (u16*)(ws + 49807360);     // 25,165,824 B
  float* lp  = (float*)(ws + 74973184);   //     65,536 B   (total 75,038,720)

  cvt_bf16<<<2048, 256, 0, stream>>>(x, xb, 8192 * 1024 / 4);
  cvt_bf16<<<768, 256, 0, stream>>>(W, Wb, 768 * 1024 / 4);
  buildK<<<256, 256, 0, stream>>>(keys, Ki8);
  buildV<<<256, 256, 0, stream>>>(values, Vi8);
  gemm1<<<dim3(64, 6), 256, 0, stream>>>(xb, Wb, bias, out);
  rownorm8<<<8192, 384, 0, stream>>>(out, q8);
  attn<<<dim3(2, 128), 1024, 0, stream>>>(q8, Ki8, Vi8, beta, Opart, lp);
  combine<<<8192, 192, 0, stream>>>(out, Opart, lp, alpha);
}

// Round 8
// 284.623 us; speedup vs baseline: 1.7505x; 1.1401x over previous
//
#include <hip/hip_runtime.h>
#include <hip/hip_bf16.h>

typedef unsigned char  u8;
typedef unsigned short u16;
typedef unsigned int   u32;
typedef __attribute__((ext_vector_type(8)))  short bf16x8;
typedef __attribute__((ext_vector_type(4)))  float f32x4;
typedef __attribute__((ext_vector_type(4)))  int   i32x4;
typedef __attribute__((ext_vector_type(16))) int   i32x16;
typedef __attribute__((ext_vector_type(4)))  u16   u16x4;

__device__ __forceinline__ u16 f2bf(float f) {
  union { float f; u32 u; } v; v.f = f;
  u32 r = v.u + 0x7FFFu + ((v.u >> 16) & 1u);   // RNE
  return (u16)(r >> 16);
}
__device__ __forceinline__ int q127(float x) { return (int)rintf(x * 127.0f); }

#define GLL16(gptr, lptr)                                                            \
  __builtin_amdgcn_global_load_lds((const __attribute__((address_space(1))) u32*)(gptr), \
                                   (__attribute__((address_space(3))) u32*)(lptr), 16, 0, 0)

// lgkm-only barrier: does NOT drain vmcnt, so global prefetches stay in flight
#define BARRIER_LGKM() do { asm volatile("s_waitcnt lgkmcnt(0)" ::: "memory"); \
                            __builtin_amdgcn_s_barrier(); } while (0)

// ---------------------------------------------------------------- f32 -> bf16
__global__ __launch_bounds__(256) void cvt_bf16(const float* __restrict__ in,
                                                u16* __restrict__ out, int n4) {
  int i = blockIdx.x * blockDim.x + threadIdx.x;
  int stride = gridDim.x * blockDim.x;
  for (; i < n4; i += stride) {
    float4 v = ((const float4*)in)[i];
    u16x4 o = { f2bf(v.x), f2bf(v.y), f2bf(v.z), f2bf(v.w) };
    ((u16x4*)out)[i] = o;
  }
}

// ------------- keys [16384][768] f32 -> Ki8, layout [d16=48][key=16384][16B] i8
// Ki8[d16][key][e] = q127(keys[key][d16*16+e]), e in 0..15
__global__ __launch_bounds__(256) void buildK(const float* __restrict__ in,
                                              u8* __restrict__ out) {
  __shared__ float tile[64][65];
  int kt = blockIdx.x;            // 64 keys per block
  int t = threadIdx.x;
  int r0 = t >> 6, c = t & 63;
  for (int dc = 0; dc < 12; ++dc) {
    if (dc) __syncthreads();
#pragma unroll
    for (int i = 0; i < 16; ++i) {
      int r = i * 4 + r0;
      tile[r][c] = in[(size_t)(kt * 64 + r) * 768 + dc * 64 + c];
    }
    __syncthreads();
    int d16l = t >> 6, key = t & 63;   // d16l in 0..3
    u32 wd[4];
#pragma unroll
    for (int g = 0; g < 4; ++g) {
      u32 v = 0;
#pragma unroll
      for (int j = 0; j < 4; ++j)
        v |= (u32)(q127(tile[key][d16l * 16 + g * 4 + j]) & 255) << (8 * j);
      wd[g] = v;
    }
    uint4 val = { wd[0], wd[1], wd[2], wd[3] };
    *(uint4*)(out + ((size_t)(dc * 4 + d16l) * 16384 + (size_t)(kt * 64 + key)) * 16) = val;
  }
}

// ------------- values [16384][768] f32 -> Vi8, layout [k16=1024][d=768][16B] i8
// Vi8[k16][d][e] = q127(values[k16*16+e][d]), e in 0..15
__global__ __launch_bounds__(256) void buildV(const float* __restrict__ in,
                                              u8* __restrict__ out) {
  __shared__ float tile[64][65];
  int kt = blockIdx.x;            // 64 keys per block
  int t = threadIdx.x;
  int r0 = t >> 6, c = t & 63;
  for (int dc = 0; dc < 12; ++dc) {
    if (dc) __syncthreads();
#pragma unroll
    for (int i = 0; i < 16; ++i) {
      int r = i * 4 + r0;
      tile[r][c] = in[(size_t)(kt * 64 + r) * 768 + dc * 64 + c];
    }
    __syncthreads();
    int k16l = t >> 6, dl = t & 63;    // k16l in 0..3
    u32 wd[4];
#pragma unroll
    for (int g = 0; g < 4; ++g) {
      u32 v = 0;
#pragma unroll
      for (int j = 0; j < 4; ++j)
        v |= (u32)(q127(tile[k16l * 16 + g * 4 + j][dl]) & 255) << (8 * j);
      wd[g] = v;
    }
    uint4 val = { wd[0], wd[1], wd[2], wd[3] };
    *(uint4*)(out + ((size_t)(kt * 4 + k16l) * 768 + (size_t)(dc * 64 + dl)) * 16) = val;
  }
}

// ---------------------------------------------------------------- GEMM1 (bf16)
__global__ __launch_bounds__(256) void gemm1(const u16* __restrict__ A,
                                             const u16* __restrict__ B,
                                             const float* __restrict__ bias,
                                             float* __restrict__ C) {
  __shared__ u16 As[2][128 * 32];
  __shared__ u16 Bs[2][128 * 32];
  int t = threadIdx.x;
  int brow = blockIdx.x * 128, bcol = blockIdx.y * 128;
  int w = t >> 6, l = t & 63;
  int l15 = l & 15, l4 = l >> 4;
  int wr = (w >> 1) * 64, wc = (w & 1) * 64;
  f32x4 acc[4][4];
#pragma unroll
  for (int i = 0; i < 4; ++i)
#pragma unroll
    for (int j = 0; j < 4; ++j) acc[i][j] = f32x4{0.f, 0.f, 0.f, 0.f};

  auto stage = [&](int buf, int kt) {
#pragma unroll
    for (int i = 0; i < 2; ++i) {
      int id = t + i * 256;
      int row = id >> 2, c = id & 3;
      int cs = (c ^ (row & 3)) * 8;
      GLL16(A + (size_t)(brow + row) * 1024 + kt * 32 + cs, &As[buf][id * 8]);
      GLL16(B + (size_t)(bcol + row) * 1024 + kt * 32 + cs, &Bs[buf][id * 8]);
    }
  };
  stage(0, 0);
  for (int kt = 0; kt < 32; ++kt) {
    int buf = kt & 1;
    __syncthreads();
    if (kt < 31) stage(buf ^ 1, kt + 1);
    bf16x8 a[4], b[4];
#pragma unroll
    for (int mf = 0; mf < 4; ++mf) {
      int row = wr + mf * 16 + l15;
      a[mf] = *(const bf16x8*)&As[buf][row * 32 + ((l4 ^ (row & 3)) * 8)];
    }
#pragma unroll
    for (int nf = 0; nf < 4; ++nf) {
      int row = wc + nf * 16 + l15;
      b[nf] = *(const bf16x8*)&Bs[buf][row * 32 + ((l4 ^ (row & 3)) * 8)];
    }
#pragma unroll
    for (int mf = 0; mf < 4; ++mf)
#pragma unroll
      for (int nf = 0; nf < 4; ++nf)
        acc[mf][nf] = __builtin_amdgcn_mfma_f32_16x16x32_bf16(a[mf], b[nf], acc[mf][nf], 0, 0, 0);
  }
#pragma unroll
  for (int mf = 0; mf < 4; ++mf)
#pragma unroll
    for (int nf = 0; nf < 4; ++nf) {
      int col = bcol + wc + nf * 16 + l15;
      float bv = bias[col];
#pragma unroll
      for (int j = 0; j < 4; ++j) {
        int row = brow + wr + mf * 16 + l4 * 4 + j;
        C[(size_t)row * 768 + col] = acc[mf][nf][j] + bv;
      }
    }
}

// ---------------------------------------------------------------- row L2-normalize -> i8
__global__ __launch_bounds__(384) void rownorm8(const float* __restrict__ P,
                                                u8* __restrict__ q8) {
  int row = blockIdx.x, t = threadIdx.x;
  size_t base = (size_t)row * 768;
  float2 v = *(const float2*)&P[base + 2 * t];
  float ss = v.x * v.x + v.y * v.y;
#pragma unroll
  for (int o = 32; o; o >>= 1) ss += __shfl_xor(ss, o);
  __shared__ float wsum[6];
  if ((t & 63) == 0) wsum[t >> 6] = ss;
  __syncthreads();
  float tot = wsum[0] + wsum[1] + wsum[2] + wsum[3] + wsum[4] + wsum[5];
  float inv = 1.0f / fmaxf(sqrtf(tot), 1e-12f);
  int a = q127(v.x * inv), b = q127(v.y * inv);
  *(u16*)(q8 + base + 2 * t) = (u16)((a & 255) | ((b & 255) << 8));
}

// ---------------------------------------------------------------- fused attention, i8
// 16 waves, BM=64 q, KVBLK=512, nsplit=2, d-slice 48/wave PV. Round-6 schedule
// (Ps dbuf, one lgkm-only barrier/iter, cross-barrier K prefetch, setprio).
// Round-8: all operands are native 16B vectors — Ki8 [d16][key][16B],
// Vi8 [k16][d][16B], Qlds/Ps i32x4 [chunk16][q] — one dwordx4/b128 per operand,
// no union repacks. A/B use identical (lane,byte)->k maps (permutation cancels).
__global__ __launch_bounds__(1024, 4) void attn(const u8* __restrict__ q8,
                                                const u8* __restrict__ Ki8,
                                                const u8* __restrict__ Vi8,
                                                const float* __restrict__ beta_p,
                                                u16* __restrict__ Opart,
                                                float* __restrict__ lpart) {
  __shared__ i32x4 Qlds[48 * 64];     // 48 KB [c16][q]
  __shared__ i32x4 Ps[2][32 * 64];    // 2 x 32 KB [kc16][q]
  __shared__ float lred[16][64];      // 4 KB
  int t = threadIdx.x;
  int w = t >> 6, l = t & 63;
  int ql = l & 31, hi = l >> 5;        // 32x32 lanes
  int l15 = l & 15, l4g = l >> 4;      // 16x16 lanes (0..3)
  int split = blockIdx.x, qb = blockIdx.y;
  int qrow0 = qb * 64;
  float beta = beta_p[0];
  float c1 = beta * 1.44269504089f / 16129.0f;   // int logit -> log2 domain
  float pscale = 127.0f / expf(beta);            // P -> i8
  float ovs = expf(beta) / 16129.0f;             // i32 PV acc -> float

  // ---- stage Q [64 q][768 d] i8 into [c16][q] (once)
#pragma unroll
  for (int i = 0; i < 3; ++i) {
    int id = i * 1024 + t;             // id = c16*64 + q
    int c16 = id >> 6, q = id & 63;
    Qlds[id] = *(const i32x4*)(q8 + (size_t)(qrow0 + q) * 768 + (size_t)c16 * 16);
  }

  i32x4 oacc[4][3];
#pragma unroll
  for (int mq = 0; mq < 4; ++mq)
#pragma unroll
    for (int nd = 0; nd < 3; ++nd) oacc[mq][nd] = i32x4{0, 0, 0, 0};
  float lsum0 = 0.f, lsum1 = 0.f;

  int kbase = split * 8192;
  // K entries [d16][key]; fold lane's hi and key into base
  const i32x4* Kp = (const i32x4*)Ki8 + (size_t)hi * 16384 + (size_t)(kbase + w * 32 + ql);
  // V entries [k16][d]; fold lane's l4g and d into base
  const i32x4* Vp = (const i32x4*)Vi8 + ((size_t)(kbase >> 4) + l4g) * 768 + (size_t)(w * 48 + l15);

  // preload K tile 0 (3-step lookahead, in flight across the staging barrier)
  i32x4 kb[3];
#pragma unroll
  for (int s = 0; s < 3; ++s) kb[s] = Kp[(size_t)(2 * s) * 16384];

  __syncthreads();

  for (int it = 0; it < 16; ++it) {
    int n0 = it * 512;
    const i32x4* kp = Kp + n0;
    i32x4* psb = &Ps[it & 1][0];

    // ---------- QK^T: wave w -> keys [n0+w*32,+32), all 64 q; 24 steps of K=32
    i32x16 sacc0 = (i32x16)0;
    i32x16 sacc1 = (i32x16)0;
    __builtin_amdgcn_s_setprio(1);
#pragma unroll
    for (int ks = 0; ks < 24; ++ks) {
      i32x4 av = kb[ks % 3];
      if (ks < 21) kb[ks % 3] = kp[(size_t)(2 * (ks + 3)) * 16384];
      i32x4 q0 = Qlds[(2 * ks + hi) * 64 + ql];
      i32x4 q1 = Qlds[(2 * ks + hi) * 64 + ql + 32];
      sacc0 = __builtin_amdgcn_mfma_i32_32x32x32_i8(av, q0, sacc0, 0, 0, 0);
      sacc1 = __builtin_amdgcn_mfma_i32_32x32x32_i8(av, q1, sacc1, 0, 0, 0);
    }
    __builtin_amdgcn_s_setprio(0);

    // ---------- exp (no max), lsum, quantize P -> i8 -> Ps[it&1]
    // sacc reg r: key-in-wave = (r&3) + 8*(r>>2) + 4*hi ; q = ql (+32 for sacc1)
    // write u32: kc16 = 2w + (rg>>1), dword-in-16B = 2*(rg&1) + hi
#pragma unroll
    for (int qf = 0; qf < 2; ++qf) {
      int q = ql + qf * 32;
      float lacc = 0.f;
#pragma unroll
      for (int rg = 0; rg < 4; ++rg) {
        float p0, p1, p2, p3;
        if (qf == 0) {
          p0 = exp2f(c1 * (float)sacc0[rg * 4 + 0]); p1 = exp2f(c1 * (float)sacc0[rg * 4 + 1]);
          p2 = exp2f(c1 * (float)sacc0[rg * 4 + 2]); p3 = exp2f(c1 * (float)sacc0[rg * 4 + 3]);
        } else {
          p0 = exp2f(c1 * (float)sacc1[rg * 4 + 0]); p1 = exp2f(c1 * (float)sacc1[rg * 4 + 1]);
          p2 = exp2f(c1 * (float)sacc1[rg * 4 + 2]); p3 = exp2f(c1 * (float)sacc1[rg * 4 + 3]);
        }
        lacc += (p0 + p1) + (p2 + p3);
        int i0 = (int)rintf(fminf(p0 * pscale, 127.f));
        int i1 = (int)rintf(fminf(p1 * pscale, 127.f));
        int i2 = (int)rintf(fminf(p2 * pscale, 127.f));
        int i3 = (int)rintf(fminf(p3 * pscale, 127.f));
        u32 pk = (u32)i0 | ((u32)i1 << 8) | ((u32)i2 << 16) | ((u32)i3 << 24);
        ((u32*)psb)[((2 * w + (rg >> 1)) * 64 + q) * 4 + 2 * (rg & 1) + hi] = pk;
      }
      if (qf == 0) lsum0 += lacc; else lsum1 += lacc;
    }

    // ---------- prefetch K for next tile (stays in flight across barrier)
    if (it < 15) {
      const i32x4* kpn = Kp + (size_t)(it + 1) * 512;
#pragma unroll
      for (int s = 0; s < 3; ++s) kb[s] = kpn[(size_t)(2 * s) * 16384];
    }
    // ---------- preload V for kstep 0 (no Ps dependency -> before barrier)
    i32x4 vb[2][3];
#pragma unroll
    for (int nd = 0; nd < 3; ++nd)
      vb[0][nd] = Vp[(size_t)(n0 >> 4) * 768 + nd * 16];

    BARRIER_LGKM();   // P(it) visible; kb/vb loads NOT drained

    // ---------- PV: O[64 q][48 d per wave] += P * V  (16x16x64 i8, 8 ksteps)
    __builtin_amdgcn_s_setprio(1);
#pragma unroll
    for (int ksv = 0; ksv < 8; ++ksv) {
      int cur = ksv & 1;
      if (ksv < 7) {
#pragma unroll
        for (int nd = 0; nd < 3; ++nd)
          vb[cur ^ 1][nd] = Vp[((size_t)(n0 >> 4) + (ksv + 1) * 4) * 768 + nd * 16];
      }
#pragma unroll
      for (int mq = 0; mq < 4; ++mq) {
        i32x4 pa = psb[(4 * ksv + l4g) * 64 + mq * 16 + l15];
        oacc[mq][0] = __builtin_amdgcn_mfma_i32_16x16x64_i8(pa, vb[cur][0], oacc[mq][0], 0, 0, 0);
        oacc[mq][1] = __builtin_amdgcn_mfma_i32_16x16x64_i8(pa, vb[cur][1], oacc[mq][1], 0, 0, 0);
        oacc[mq][2] = __builtin_amdgcn_mfma_i32_16x16x64_i8(pa, vb[cur][2], oacc[mq][2], 0, 0, 0);
      }
    }
    __builtin_amdgcn_s_setprio(0);
    // no second barrier: Ps double-buffered; rewrite of Ps[it&1] is after the NEXT barrier
  }

  // ---- l reduction: lanes l, l^32 share q; wave covers its 32 keys
  {
    float s0 = lsum0 + __shfl_xor(lsum0, 32);
    float s1 = lsum1 + __shfl_xor(lsum1, 32);
    if (hi == 0) { lred[w][ql] = s0; lred[w][ql + 32] = s1; }
  }
  __syncthreads();
  if (t < 64) {
    float s = 0.f;
#pragma unroll
    for (int ww = 0; ww < 16; ++ww) s += lred[ww][t];
    lpart[split * 8192 + qrow0 + t] = s;
  }

  // ---- write unnormalized O partial (bf16); 16x16 C: row=(l>>4)*4+j, col=l&15
#pragma unroll
  for (int mq = 0; mq < 4; ++mq)
#pragma unroll
    for (int nd = 0; nd < 3; ++nd) {
      int col = w * 48 + nd * 16 + l15;
#pragma unroll
      for (int j = 0; j < 4; ++j) {
        int row = qrow0 + mq * 16 + l4g * 4 + j;
        Opart[((size_t)split * 8192 + row) * 768 + col] = f2bf((float)oacc[mq][nd][j] * ovs);
      }
    }
}

// ---------------------------------------------------------------- final combine
__global__ __launch_bounds__(192) void combine(float* __restrict__ out,
                                               const u16* __restrict__ Opart,
                                               const float* __restrict__ lpart,
                                               const float* __restrict__ alpha_p) {
  int row = blockIdx.x, t = threadIdx.x;
  float scale = alpha_p[0] / (lpart[row] + lpart[8192 + row]);
  size_t base = (size_t)row * 768 + t * 4;
  u16x4 o0 = *(const u16x4*)&Opart[base];
  u16x4 o1 = *(const u16x4*)&Opart[(size_t)6291456 + base];
  float4 cur = *(float4*)&out[base];
  union { u32 u; float f; } c0, c1, c2, c3, d0_, d1_, d2_, d3_;
  c0.u = (u32)o0[0] << 16; c1.u = (u32)o0[1] << 16; c2.u = (u32)o0[2] << 16; c3.u = (u32)o0[3] << 16;
  d0_.u = (u32)o1[0] << 16; d1_.u = (u32)o1[1] << 16; d2_.u = (u32)o1[2] << 16; d3_.u = (u32)o1[3] << 16;
  cur.x += (c0.f + d0_.f) * scale;
  cur.y += (c1.f + d1_.f) * scale;
  cur.z += (c2.f + d2_.f) * scale;
  cur.w += (c3.f + d3_.f) * scale;
  *(float4*)&out[base] = cur;
}

// ---------------------------------------------------------------- launch
extern "C" void kernel_launch(void* const* d_in, const int* in_sizes, int n_in,
                              void* d_out, int out_size, void* d_ws, size_t ws_size,
                              hipStream_t stream) {
  const float* x      = (const float*)d_in[0];   // [8192][1024]
  const float* W      = (const float*)d_in[1];   // [768][1024]
  const float* bias   = (const float*)d_in[2];   // [768]
  const float* keys   = (const float*)d_in[3];   // [16384][768]
  const float* values = (const float*)d_in[4];   // [16384][768]
  const float* beta   = (const float*)d_in[5];
  const float* alpha  = (const float*)d_in[6];
  float* out = (float*)d_out;

  char* ws = (char*)d_ws;
  u16* xb    = (u16*)(ws + 0);            // 16,777,216 B
  u16* Wb    = (u16*)(ws + 16777216);     //  1,572,864 B
  u8*  Ki8   = (u8*) (ws + 18350080);     // 12,582,912 B
  u8*  Vi8   = (u8*) (ws + 30932992);     // 12,582,912 B
  u8*  q8    = (u8*) (ws + 43515904);     //  6,291,456 B
  u16* Opart = (u16*)(ws + 49807360);     // 25,165,824 B
  float* lp  = (float*)(ws + 74973184);   //     65,536 B   (total 75,038,720)

  cvt_bf16<<<2048, 256, 0, stream>>>(x, xb, 8192 * 1024 / 4);
  cvt_bf16<<<768, 256, 0, stream>>>(W, Wb, 768 * 1024 / 4);
  buildK<<<256, 256, 0, stream>>>(keys, Ki8);
  buildV<<<256, 256, 0, stream>>>(values, Vi8);
  gemm1<<<dim3(64, 6), 256, 0, stream>>>(xb, Wb, bias, out);
  rownorm8<<<8192, 384, 0, stream>>>(out, q8);
  attn<<<dim3(2, 128), 1024, 0, stream>>>(q8, Ki8, Vi8, beta, Opart, lp);
  combine<<<8192, 192, 0, stream>>>(out, Opart, lp, alpha);
}